// Round 6
// baseline (111.195 us; speedup 1.0000x reference)
//
#include <hip/hip_runtime.h>
#include <math.h>

#define H 2048
#define V 50257
#define M 64
#define NEG_BIG (-1.0e30f)

#define NB5 3142   // ceil(V/16): logits blocks, 8 waves x 2 rows = 16 rows/block
#define NB6 197    // ceil(V/256)
#define NWARM 256  // warm blocks per host kernel (each warms 8 rows = 64 KB)

typedef float f4 __attribute__((ext_vector_type(4)));

__device__ inline f4 ntload(const f4* p) { return __builtin_nontemporal_load(p); }
__device__ inline float dot4(f4 a, f4 b) { return a.x*b.x + a.y*b.y + a.z*b.z + a.w*b.w; }

__device__ inline float wred_sum(float v) {
#pragma unroll
    for (int o = 32; o >= 1; o >>= 1) v += __shfl_down(v, o);
    return v;  // lane 0 holds the sum
}

// Warm 64 KB of out_w (rows 8q..8q+8) into L2 with regular (allocating) loads.
__device__ inline void warm_outw(const float* __restrict__ out_w, int q, int t,
                                 float* __restrict__ dummy) {
    const f4* w4 = (const f4*)out_w + (size_t)q * 4096;   // 4096 f4 = 64 KB
    float acc = 0.f;
#pragma unroll 4
    for (int i = t; i < 4096; i += 256) {
        f4 v = w4[i];
        acc += v.x + v.y + v.z + v.w;
    }
    if (acc == -12345.678f) dummy[0] = acc;   // unprovable-false: keeps loads alive
}

// ---------- K_A: ALL input-independent work in one launch ----------
// blocks [0,64):    scores[m] = attn_w[m,:] . concat(emb_row, h0) + attn_b[m]
// blocks [64,832):  gh[j] = w_hh[j,:] . h0 + b_hh[j]          (6144 rows, 2/wave)
// blocks [832,1344): pc[r] = comb_w[r, 0:H] . emb_row         (2048 rows, 1/wave)
__global__ void k_indep(const int* __restrict__ tok, const float* __restrict__ hidden,
                        const float* __restrict__ emb, const float* __restrict__ attn_w,
                        const float* __restrict__ attn_b, const float* __restrict__ w_hh,
                        const float* __restrict__ b_hh, const float* __restrict__ comb_w,
                        float* __restrict__ scores, float* __restrict__ gh,
                        float* __restrict__ pc) {
    const int t = threadIdx.x, lane = t & 63, wid = t >> 6;
    const int b = blockIdx.x;
    if (b < 64) {
        const int m = b;
        const float* erow = emb + (size_t)tok[0] * H;
        const f4* w4 = (const f4*)(attn_w + (size_t)m * 2 * H);
        float acc = 0.f;
        for (int i = t; i < 1024; i += 256) {
            f4 w = ntload(w4 + i);
            int k = i * 4;
            f4 c = (k < H) ? *(const f4*)(erow + k) : *(const f4*)(hidden + (k - H));
            acc += dot4(w, c);
        }
        __shared__ float sred[4];
        float s = wred_sum(acc);
        if (lane == 0) sred[wid] = s;
        __syncthreads();
        if (t == 0) scores[m] = sred[0] + sred[1] + sred[2] + sred[3] + attn_b[m];
    } else if (b < 832) {
        const int j0 = ((b - 64) * 4 + wid) * 2;   // rows 0..6143
        const f4* w0 = (const f4*)(w_hh + (size_t)j0 * H);
        const f4* w1 = (const f4*)(w_hh + (size_t)(j0 + 1) * H);
        const f4* h4 = (const f4*)hidden;
        float a0 = 0.f, a1 = 0.f;
#pragma unroll
        for (int it = 0; it < 8; ++it) {
            int i = it * 64 + lane;
            f4 hv = h4[i];
            a0 += dot4(ntload(w0 + i), hv);
            a1 += dot4(ntload(w1 + i), hv);
        }
        a0 = wred_sum(a0); a1 = wred_sum(a1);
        if (lane == 0) { gh[j0] = a0 + b_hh[j0]; gh[j0 + 1] = a1 + b_hh[j0 + 1]; }
    } else {
        const int r = (b - 832) * 4 + wid;         // rows 0..2047
        const float* erow = emb + (size_t)tok[0] * H;
        const f4* w4 = (const f4*)(comb_w + (size_t)r * 2 * H);   // first half of row r
        const f4* e4 = (const f4*)erow;
        float acc = 0.f;
#pragma unroll
        for (int it = 0; it < 8; ++it) {
            int i = it * 64 + lane;   // 512 f4 = cols 0..2047
            acc += dot4(ntload(w4 + i), e4[i]);
        }
        acc = wred_sum(acc);
        if (lane == 0) pc[r] = acc;
    }
}

// ---------- K_B: softmax + attn_applied (blocks 0..7) + out_w warm (blocks 8..263) ----------
__global__ void k_sm_aa(const float* __restrict__ scores, const float* __restrict__ enc,
                        float* __restrict__ aw_out, float* __restrict__ attn_applied,
                        const float* __restrict__ out_w, float* __restrict__ dummy) {
    int t = threadIdx.x;
    if (blockIdx.x >= 8) {
        warm_outw(out_w, blockIdx.x - 8, t, dummy);   // rows 0..2047
        return;
    }
    __shared__ float w[M];
    if (t < 64) {
        float s = scores[t];
        float mx = s;
#pragma unroll
        for (int o = 32; o >= 1; o >>= 1) mx = fmaxf(mx, __shfl_xor(mx, o));
        float e = expf(s - mx);
        float sum = e;
#pragma unroll
        for (int o = 32; o >= 1; o >>= 1) sum += __shfl_xor(sum, o);
        float aw = e / sum;
        w[t] = aw;
        if (blockIdx.x == 0) aw_out[t] = aw;
    }
    __syncthreads();
    int h = blockIdx.x * 256 + t;  // 8 blocks x 256 = 2048
    float acc = 0.f;
#pragma unroll 8
    for (int m = 0; m < M; ++m) acc += w[m] * enc[(size_t)m * H + h];
    attn_applied[h] = acc;
}

// ---------- K_C: x[r] = relu(pc[r] + comb_w[r, H:2H] . aa + comb_b[r]) + warm ----------
__global__ void k_combine2(const float* __restrict__ comb_w, const float* __restrict__ comb_b,
                           const float* __restrict__ aa, const float* __restrict__ pc,
                           float* __restrict__ x_out, const float* __restrict__ out_w,
                           float* __restrict__ dummy) {
    int t = threadIdx.x;
    if (blockIdx.x >= 512) {
        warm_outw(out_w, NWARM + (blockIdx.x - 512), t, dummy);   // rows 2048..4095
        return;
    }
    int r = (blockIdx.x * 256 + t) >> 6;  // 2048 rows, wave per row
    int lane = t & 63;
    const f4* w4 = (const f4*)(comb_w + (size_t)r * 2 * H + H);  // second half
    const f4* a4 = (const f4*)aa;
    float acc = 0.f;
#pragma unroll
    for (int it = 0; it < 8; ++it) {
        int i = it * 64 + lane;   // 512 f4 = cols H..2H-1
        acc += dot4(ntload(w4 + i), a4[i]);
    }
    acc = wred_sum(acc);
    if (lane == 0) x_out[r] = fmaxf(pc[r] + acc + comb_b[r], 0.f);
}

// ---------- K_D: gi = w_ih . x, gates with precomputed gh -> h_new ----------
__global__ void k_gates(const float* __restrict__ hidden, const float* __restrict__ w_ih,
                        const float* __restrict__ b_ih, const float* __restrict__ x,
                        const float* __restrict__ gh, float* __restrict__ h_out) {
    int j = (blockIdx.x * blockDim.x + threadIdx.x) >> 6;  // 2048 rows
    int lane = threadIdx.x & 63;
    const f4* x4 = (const f4*)x;
    const f4* wr = (const f4*)(w_ih + (size_t)j * H);
    const f4* wz = (const f4*)(w_ih + (size_t)(H + j) * H);
    const f4* wn = (const f4*)(w_ih + (size_t)(2 * H + j) * H);
    float ar = 0.f, az = 0.f, an = 0.f;
#pragma unroll
    for (int it = 0; it < 8; ++it) {
        int i = it * 64 + lane;
        f4 xv = x4[i];
        ar += dot4(ntload(wr + i), xv);
        az += dot4(ntload(wz + i), xv);
        an += dot4(ntload(wn + i), xv);
    }
    ar = wred_sum(ar); az = wred_sum(az); an = wred_sum(an);
    if (lane == 0) {
        float r = 1.f / (1.f + expf(-(ar + b_ih[j] + gh[j])));
        float z = 1.f / (1.f + expf(-(az + b_ih[H + j] + gh[H + j])));
        float n = tanhf(an + b_ih[2 * H + j] + r * gh[2 * H + j]);
        h_out[j] = (1.f - z) * n + z * hidden[j];
    }
}

// ---------- K_E: logits GEMV, 512 thr, 2 rows/wave + per-block online LSE partial ----------
__global__ void __launch_bounds__(512) k_logits(
        const float* __restrict__ out_w, const float* __restrict__ out_b,
        const float* __restrict__ hnew, float* __restrict__ logits,
        float2* __restrict__ part) {
    const int t = threadIdx.x, lane = t & 63, wid = t >> 6;  // 8 waves
    const int base = blockIdx.x * 16 + wid * 2;
    const int row0 = base, row1 = base + 1;
    const bool v0 = row0 < V, v1 = row1 < V;
    const f4* w0 = (const f4*)(out_w + (size_t)(v0 ? row0 : 0) * H);
    const f4* w1 = (const f4*)(out_w + (size_t)(v1 ? row1 : 0) * H);
    const f4* h4 = (const f4*)hnew;
    float a0 = 0.f, a1 = 0.f;
#pragma unroll
    for (int it = 0; it < 8; ++it) {
        int i = it * 64 + lane;
        f4 h = h4[i];                 // L1/L2-resident
        a0 += dot4(ntload(w0 + i), h);
        a1 += dot4(ntload(w1 + i), h);
    }
    a0 = wred_sum(a0); a1 = wred_sum(a1);
    float m = NEG_BIG, s = 0.f;
    if (lane == 0) {
        if (v0) { float lg = a0 + out_b[row0]; logits[row0] = lg; m = lg; s = 1.f; }
        if (v1) { float lg = a1 + out_b[row1]; logits[row1] = lg;
                  float mm = fmaxf(m, lg); s = s * expf(m - mm) + expf(lg - mm); m = mm; }
    }
    __shared__ float2 lms[8];
    if (lane == 0) lms[wid] = make_float2(m, s);
    __syncthreads();
    if (t == 0) {
        float gm = NEG_BIG, gs = 0.f;
#pragma unroll
        for (int i2 = 0; i2 < 8; ++i2) {
            float m2 = lms[i2].x, s2 = lms[i2].y;
            float mm = fmaxf(gm, m2);
            gs = gs * expf(gm - mm) + s2 * expf(m2 - mm);
            gm = mm;
        }
        part[blockIdx.x] = make_float2(gm, gs);
    }
}

// ---------- K_F: reduce NB5 partials (L2-resident) + in-place log-softmax ----------
__global__ void k_logsoftmax(float* __restrict__ logits, const float2* __restrict__ part) {
    const int t = threadIdx.x;
    float m = NEG_BIG, s = 0.f;
    for (int i = t; i < NB5; i += 256) {
        float2 p = part[i];
        float mm = fmaxf(m, p.x);
        s = s * expf(m - mm) + p.y * expf(p.x - mm);
        m = mm;
    }
    __shared__ float sm[256], ss[256];
    sm[t] = m; ss[t] = s;
    __syncthreads();
    for (int o = 128; o >= 1; o >>= 1) {
        if (t < o) {
            float m2 = sm[t + o], s2 = ss[t + o];
            float mm = fmaxf(sm[t], m2);
            ss[t] = ss[t] * expf(sm[t] - mm) + s2 * expf(m2 - mm);
            sm[t] = mm;
        }
        __syncthreads();
    }
    float lse = sm[0] + logf(ss[0]);
    int i = blockIdx.x * 256 + t;
    if (i < V) logits[i] -= lse;
}

extern "C" void kernel_launch(void* const* d_in, const int* in_sizes, int n_in,
                              void* d_out, int out_size, void* d_ws, size_t ws_size,
                              hipStream_t stream) {
    const int*   tok     = (const int*)d_in[0];
    const float* hidden  = (const float*)d_in[1];   // [1,1,H]
    const float* enc     = (const float*)d_in[2];   // [M,H]
    const float* emb     = (const float*)d_in[3];   // [V,H]
    const float* attn_w  = (const float*)d_in[4];   // [M,2H]
    const float* attn_b  = (const float*)d_in[5];   // [M]
    const float* comb_w  = (const float*)d_in[6];   // [H,2H]
    const float* comb_b  = (const float*)d_in[7];   // [H]
    const float* w_ih    = (const float*)d_in[8];   // [3H,H]
    const float* w_hh    = (const float*)d_in[9];   // [3H,H]
    const float* b_ih    = (const float*)d_in[10];  // [3H]
    const float* b_hh    = (const float*)d_in[11];  // [3H]
    const float* out_w   = (const float*)d_in[12];  // [V,H]
    const float* out_b   = (const float*)d_in[13];  // [V]

    float* out = (float*)d_out;
    float* logp  = out;             // [V]
    float* hout  = out + V;         // [H]
    float* awout = out + V + H;     // [M]

    float* ws = (float*)d_ws;
    float*  AA   = ws;                      // [2048] attn_applied
    float*  X    = ws + 2048;               // [2048] relu(combine)
    float*  SC   = ws + 4096;               // [64]   raw scores
    float*  GH   = ws + 4160;               // [6144] gh = w_hh.h0 + b_hh
    float*  PC   = ws + 10304;              // [2048] partial combine (emb half)
    float*  DUM  = ws + 12352;              // [1]    warm-read sink
    float2* PART = (float2*)(ws + 12354);   // [NB5]  lse partials (byte off 49416, 8-aligned)

    k_indep     <<<1344,      256, 0, stream>>>(tok, hidden, emb, attn_w, attn_b, w_hh, b_hh,
                                                comb_w, SC, GH, PC);
    k_sm_aa     <<<8 + NWARM, 256, 0, stream>>>(SC, enc, awout, AA, out_w, DUM);
    k_combine2  <<<512+NWARM, 256, 0, stream>>>(comb_w, comb_b, AA, PC, X, out_w, DUM);
    k_gates     <<<512,       256, 0, stream>>>(hidden, w_ih, b_ih, X, GH, hout);
    k_logits    <<<NB5,       512, 0, stream>>>(out_w, out_b, hout, logp, PART);
    k_logsoftmax<<<NB6,       256, 0, stream>>>(logp, PART);
}

// Round 7
// 104.303 us; speedup vs baseline: 1.0661x; 1.0661x over previous
//
#include <hip/hip_runtime.h>
#include <math.h>

#define H 2048
#define V 50257
#define M 64
#define NEG_BIG (-1.0e30f)

#define NB5 4189   // ceil(V/12): logits blocks, 4 waves x 3 rows
#define NB6 197    // ceil(V/256)

typedef float f4 __attribute__((ext_vector_type(4)));

__device__ inline f4 ntload(const f4* p) { return __builtin_nontemporal_load(p); }
__device__ inline float dot4(f4 a, f4 b) { return a.x*b.x + a.y*b.y + a.z*b.z + a.w*b.w; }

__device__ inline float wred_sum(float v) {
#pragma unroll
    for (int o = 32; o >= 1; o >>= 1) v += __shfl_down(v, o);
    return v;  // lane 0 holds the sum
}

// ---------- K_A: ALL input-independent work in one launch ----------
// blocks [0,64):    scores[m] = attn_w[m,:] . concat(emb_row, h0) + attn_b[m]
// blocks [64,832):  gh[j] = w_hh[j,:] . h0 + b_hh[j]          (6144 rows, 2/wave)
// blocks [832,1344): pc[r] = comb_w[r, 0:H] . emb_row         (2048 rows, 1/wave)
__global__ void k_indep(const int* __restrict__ tok, const float* __restrict__ hidden,
                        const float* __restrict__ emb, const float* __restrict__ attn_w,
                        const float* __restrict__ attn_b, const float* __restrict__ w_hh,
                        const float* __restrict__ b_hh, const float* __restrict__ comb_w,
                        float* __restrict__ scores, float* __restrict__ gh,
                        float* __restrict__ pc) {
    const int t = threadIdx.x, lane = t & 63, wid = t >> 6;
    const int b = blockIdx.x;
    if (b < 64) {
        const int m = b;
        const float* erow = emb + (size_t)tok[0] * H;
        const f4* w4 = (const f4*)(attn_w + (size_t)m * 2 * H);
        float acc = 0.f;
        for (int i = t; i < 1024; i += 256) {
            f4 w = ntload(w4 + i);
            int k = i * 4;
            f4 c = (k < H) ? *(const f4*)(erow + k) : *(const f4*)(hidden + (k - H));
            acc += dot4(w, c);
        }
        __shared__ float sred[4];
        float s = wred_sum(acc);
        if (lane == 0) sred[wid] = s;
        __syncthreads();
        if (t == 0) scores[m] = sred[0] + sred[1] + sred[2] + sred[3] + attn_b[m];
    } else if (b < 832) {
        const int j0 = ((b - 64) * 4 + wid) * 2;   // rows 0..6143
        const f4* w0 = (const f4*)(w_hh + (size_t)j0 * H);
        const f4* w1 = (const f4*)(w_hh + (size_t)(j0 + 1) * H);
        const f4* h4 = (const f4*)hidden;
        float a0 = 0.f, a1 = 0.f;
#pragma unroll
        for (int it = 0; it < 8; ++it) {
            int i = it * 64 + lane;
            f4 hv = h4[i];
            a0 += dot4(ntload(w0 + i), hv);
            a1 += dot4(ntload(w1 + i), hv);
        }
        a0 = wred_sum(a0); a1 = wred_sum(a1);
        if (lane == 0) { gh[j0] = a0 + b_hh[j0]; gh[j0 + 1] = a1 + b_hh[j0 + 1]; }
    } else {
        const int r = (b - 832) * 4 + wid;         // rows 0..2047
        const float* erow = emb + (size_t)tok[0] * H;
        const f4* w4 = (const f4*)(comb_w + (size_t)r * 2 * H);   // first half of row r
        const f4* e4 = (const f4*)erow;
        float acc = 0.f;
#pragma unroll
        for (int it = 0; it < 8; ++it) {
            int i = it * 64 + lane;   // 512 f4 = cols 0..2047
            acc += dot4(ntload(w4 + i), e4[i]);
        }
        acc = wred_sum(acc);
        if (lane == 0) pc[r] = acc;
    }
}

// ---------- K_B: softmax over 64 scores + attn_applied ----------
__global__ void k_sm_aa(const float* __restrict__ scores, const float* __restrict__ enc,
                        float* __restrict__ aw_out, float* __restrict__ attn_applied) {
    __shared__ float w[M];
    int t = threadIdx.x;
    if (t < 64) {
        float s = scores[t];
        float mx = s;
#pragma unroll
        for (int o = 32; o >= 1; o >>= 1) mx = fmaxf(mx, __shfl_xor(mx, o));
        float e = expf(s - mx);
        float sum = e;
#pragma unroll
        for (int o = 32; o >= 1; o >>= 1) sum += __shfl_xor(sum, o);
        float aw = e / sum;
        w[t] = aw;
        if (blockIdx.x == 0) aw_out[t] = aw;
    }
    __syncthreads();
    int h = blockIdx.x * 256 + t;  // 8 blocks x 256 = 2048
    float acc = 0.f;
#pragma unroll 8
    for (int m = 0; m < M; ++m) acc += w[m] * enc[(size_t)m * H + h];
    attn_applied[h] = acc;
}

// ---------- K_C: x[r] = relu(pc[r] + comb_w[r, H:2H] . aa + comb_b[r]) ----------
__global__ void k_combine2(const float* __restrict__ comb_w, const float* __restrict__ comb_b,
                           const float* __restrict__ aa, const float* __restrict__ pc,
                           float* __restrict__ x_out) {
    int r = (blockIdx.x * blockDim.x + threadIdx.x) >> 6;  // 2048 rows, wave per row
    int lane = threadIdx.x & 63;
    const f4* w4 = (const f4*)(comb_w + (size_t)r * 2 * H + H);  // second half
    const f4* a4 = (const f4*)aa;
    float acc = 0.f;
#pragma unroll
    for (int it = 0; it < 8; ++it) {
        int i = it * 64 + lane;   // 512 f4 = cols H..2H-1
        acc += dot4(ntload(w4 + i), a4[i]);
    }
    acc = wred_sum(acc);
    if (lane == 0) x_out[r] = fmaxf(pc[r] + acc + comb_b[r], 0.f);
}

// ---------- K_D: gi = w_ih . x, gates with precomputed gh -> h_new ----------
__global__ void k_gates(const float* __restrict__ hidden, const float* __restrict__ w_ih,
                        const float* __restrict__ b_ih, const float* __restrict__ x,
                        const float* __restrict__ gh, float* __restrict__ h_out) {
    int j = (blockIdx.x * blockDim.x + threadIdx.x) >> 6;  // 2048 rows
    int lane = threadIdx.x & 63;
    const f4* x4 = (const f4*)x;
    const f4* wr = (const f4*)(w_ih + (size_t)j * H);
    const f4* wz = (const f4*)(w_ih + (size_t)(H + j) * H);
    const f4* wn = (const f4*)(w_ih + (size_t)(2 * H + j) * H);
    float ar = 0.f, az = 0.f, an = 0.f;
#pragma unroll
    for (int it = 0; it < 8; ++it) {
        int i = it * 64 + lane;
        f4 xv = x4[i];
        ar += dot4(ntload(wr + i), xv);
        az += dot4(ntload(wz + i), xv);
        an += dot4(ntload(wn + i), xv);
    }
    ar = wred_sum(ar); az = wred_sum(az); an = wred_sum(an);
    if (lane == 0) {
        float r = 1.f / (1.f + expf(-(ar + b_ih[j] + gh[j])));
        float z = 1.f / (1.f + expf(-(az + b_ih[H + j] + gh[H + j])));
        float n = tanhf(an + b_ih[2 * H + j] + r * gh[2 * H + j]);
        h_out[j] = (1.f - z) * n + z * hidden[j];
    }
}

// ---------- K_E: logits GEMV, 256 thr, 3 rows/wave + per-block online LSE partial ----------
__global__ void k_logits(const float* __restrict__ out_w, const float* __restrict__ out_b,
                         const float* __restrict__ hnew, float* __restrict__ logits,
                         float2* __restrict__ part) {
    const int t = threadIdx.x, lane = t & 63, wid = t >> 6;
    const int base = (blockIdx.x * 4 + wid) * 3;
    const int row0 = base, row1 = base + 1, row2 = base + 2;
    const bool v0 = row0 < V, v1 = row1 < V, v2 = row2 < V;
    const f4* w0 = (const f4*)(out_w + (size_t)(v0 ? row0 : 0) * H);
    const f4* w1 = (const f4*)(out_w + (size_t)(v1 ? row1 : 0) * H);
    const f4* w2 = (const f4*)(out_w + (size_t)(v2 ? row2 : 0) * H);
    const f4* h4 = (const f4*)hnew;
    float a0 = 0.f, a1 = 0.f, a2 = 0.f;
#pragma unroll
    for (int it = 0; it < 8; ++it) {
        int i = it * 64 + lane;
        f4 h = h4[i];                 // L1/L2-resident
        a0 += dot4(ntload(w0 + i), h);
        a1 += dot4(ntload(w1 + i), h);
        a2 += dot4(ntload(w2 + i), h);
    }
    a0 = wred_sum(a0); a1 = wred_sum(a1); a2 = wred_sum(a2);
    float m = NEG_BIG, s = 0.f;
    if (lane == 0) {
        float av[3] = {a0, a1, a2};
        bool vv[3] = {v0, v1, v2};
#pragma unroll
        for (int q = 0; q < 3; ++q) {
            if (vv[q]) {
                float lg = av[q] + out_b[base + q];
                logits[base + q] = lg;
                float mm = fmaxf(m, lg);
                s = s * expf(m - mm) + expf(lg - mm);
                m = mm;
            }
        }
    }
    __shared__ float2 lms[4];
    if (lane == 0) lms[wid] = make_float2(m, s);
    __syncthreads();
    if (t == 0) {
        float gm = NEG_BIG, gs = 0.f;
#pragma unroll
        for (int i2 = 0; i2 < 4; ++i2) {
            float m2 = lms[i2].x, s2 = lms[i2].y;
            float mm = fmaxf(gm, m2);
            gs = gs * expf(gm - mm) + s2 * expf(m2 - mm);
            gm = mm;
        }
        part[blockIdx.x] = make_float2(gm, gs);
    }
}

// ---------- K_F: reduce NB5 partials (L2-resident) + in-place log-softmax ----------
__global__ void k_logsoftmax(float* __restrict__ logits, const float2* __restrict__ part) {
    const int t = threadIdx.x;
    float m = NEG_BIG, s = 0.f;
    for (int i = t; i < NB5; i += 256) {
        float2 p = part[i];
        float mm = fmaxf(m, p.x);
        s = s * expf(m - mm) + p.y * expf(p.x - mm);
        m = mm;
    }
    __shared__ float sm[256], ss[256];
    sm[t] = m; ss[t] = s;
    __syncthreads();
    for (int o = 128; o >= 1; o >>= 1) {
        if (t < o) {
            float m2 = sm[t + o], s2 = ss[t + o];
            float mm = fmaxf(sm[t], m2);
            ss[t] = ss[t] * expf(sm[t] - mm) + s2 * expf(m2 - mm);
            sm[t] = mm;
        }
        __syncthreads();
    }
    float lse = sm[0] + logf(ss[0]);
    int i = blockIdx.x * 256 + t;
    if (i < V) logits[i] -= lse;
}

extern "C" void kernel_launch(void* const* d_in, const int* in_sizes, int n_in,
                              void* d_out, int out_size, void* d_ws, size_t ws_size,
                              hipStream_t stream) {
    const int*   tok     = (const int*)d_in[0];
    const float* hidden  = (const float*)d_in[1];   // [1,1,H]
    const float* enc     = (const float*)d_in[2];   // [M,H]
    const float* emb     = (const float*)d_in[3];   // [V,H]
    const float* attn_w  = (const float*)d_in[4];   // [M,2H]
    const float* attn_b  = (const float*)d_in[5];   // [M]
    const float* comb_w  = (const float*)d_in[6];   // [H,2H]
    const float* comb_b  = (const float*)d_in[7];   // [H]
    const float* w_ih    = (const float*)d_in[8];   // [3H,H]
    const float* w_hh    = (const float*)d_in[9];   // [3H,H]
    const float* b_ih    = (const float*)d_in[10];  // [3H]
    const float* b_hh    = (const float*)d_in[11];  // [3H]
    const float* out_w   = (const float*)d_in[12];  // [V,H]
    const float* out_b   = (const float*)d_in[13];  // [V]

    float* out = (float*)d_out;
    float* logp  = out;             // [V]
    float* hout  = out + V;         // [H]
    float* awout = out + V + H;     // [M]

    float* ws = (float*)d_ws;
    float*  AA   = ws;                      // [2048] attn_applied
    float*  X    = ws + 2048;               // [2048] relu(combine)
    float*  SC   = ws + 4096;               // [64]   raw scores
    float*  GH   = ws + 4160;               // [6144] gh = w_hh.h0 + b_hh
    float*  PC   = ws + 10304;              // [2048] partial combine (emb half)
    float2* PART = (float2*)(ws + 12352);   // [NB5]  lse partials (byte off 49408, 8-aligned)

    k_indep     <<<1344, 256, 0, stream>>>(tok, hidden, emb, attn_w, attn_b, w_hh, b_hh,
                                           comb_w, SC, GH, PC);
    k_sm_aa     <<<8,    256, 0, stream>>>(SC, enc, awout, AA);
    k_combine2  <<<512,  256, 0, stream>>>(comb_w, comb_b, AA, PC, X);
    k_gates     <<<512,  256, 0, stream>>>(hidden, w_ih, b_ih, X, GH, hout);
    k_logits    <<<NB5,  256, 0, stream>>>(out_w, out_b, hout, logp, PART);
    k_logsoftmax<<<NB6,  256, 0, stream>>>(logp, PART);
}